// Round 6
// baseline (130.068 us; speedup 1.0000x reference)
//
#include <hip/hip_runtime.h>
#include <math.h>

#define WH     256
#define NDEPTH 8
#define NBATCH 1024
#define NB     16           // batch elements per block (256 blocks, 1/CU)
#define PLANE  (WH * WH)    // 65536

typedef _Float16 h2 __attribute__((ext_vector_type(2)));

// ws layout (fp16): wsh[arr][hq8][d][hs][w]
//   arr: 0=M1 1=B1 2=M2 3=B2 ; hq8 = h>>5 ; hs = h&31 ; w inner (WIDTH)
// Exchange mailbox: 256 blocks x 16 slots of uint64 at ws + 6 MiB
// (ws >= 8 MiB, verified R2). Zeroed by transpose every launch (robust to
// ws re-poisoning); self-clearing protocol keeps it zero afterwards.
#define SLAB   (32 * WH)              // halfs per (arr,hq8,d) slab = 8192
#define HQ8BLK (NDEPTH * SLAB)        // halfs per (arr,hq8) block = 65536
#define XBUF_OFF (6u * 1024u * 1024u) // byte offset of mailbox in d_ws

// ---------------------------------------------------------------------------
// Transpose + fp32->fp16 convert. 512 blocks x 256 threads. (~10us)
// Blocks 0..255 also zero the exchange mailbox (stream-ordered before prop).
// ---------------------------------------------------------------------------
__global__ __launch_bounds__(256) void transpose_half_k(const float* __restrict__ M1,
                                                        const float* __restrict__ B1,
                                                        const float* __restrict__ M2,
                                                        const float* __restrict__ B2,
                                                        _Float16* __restrict__ wsh,
                                                        unsigned long long* __restrict__ xbuf) {
    __shared__ float tile[64][65];
    const int bid = blockIdx.x;

    if (bid < 256 && threadIdx.x < NB)          // zero mailbox for this launch
        xbuf[bid * NB + threadIdx.x] = 0ULL;

    const int arr = bid >> 7;
    const int d   = (bid >> 4) & 7;
    const int ht  = (bid >> 2) & 3;     // h-tile (64 rows) = 2 hq8 subsets
    const int wt  = bid & 3;            // w-tile

    const float* src = (arr == 0) ? M1 : (arr == 1) ? B1 : (arr == 2) ? M2 : B2;
    const float* s = src + d * PLANE;
    _Float16* ob = wsh + (size_t)((arr * 8 + ht * 2) * NDEPTH + d) * SLAB;

    const int t   = threadIdx.x;
    const int q16 = t >> 4;     // 0..15
    const int r16 = t & 15;     // 0..15

#pragma unroll
    for (int p = 0; p < 4; ++p) {        // read: float4 along h ([d][w][h])
        const int wrow = q16 + p * 16;
        const float4 v = *(const float4*)(s + (wt * 64 + wrow) * WH + ht * 64 + r16 * 4);
        tile[wrow][r16 * 4 + 0] = v.x;
        tile[wrow][r16 * 4 + 1] = v.y;
        tile[wrow][r16 * 4 + 2] = v.z;
        tile[wrow][r16 * 4 + 3] = v.w;
    }
    __syncthreads();
#pragma unroll
    for (int p = 0; p < 4; ++p) {        // write: 4 halfs along w
        const int hrow = q16 + p * 16;   // local h 0..63 (tile column)
        const int sub  = p >> 1;         // hrow>>5: which hq8 of this tile
        const int hs   = q16 + (p & 1) * 16;   // hrow & 31
        const int wl   = r16 * 4;
        union { _Float16 f[4]; uint2 u; } pk;
        pk.f[0] = (_Float16)tile[wl + 0][hrow];
        pk.f[1] = (_Float16)tile[wl + 1][hrow];
        pk.f[2] = (_Float16)tile[wl + 2][hrow];
        pk.f[3] = (_Float16)tile[wl + 3][hrow];
        *(uint2*)(ob + (size_t)sub * HQ8BLK + hs * WH + wt * 64 + wl) = pk.u;
    }
}

// ---------------------------------------------------------------------------
// Prop: 256 blocks x 512 threads, NB=16, W-SPLIT pairs.
// *** R11-R15 lore: 6 schedules (reg rings, asm rings, glds DMA rings, 1-2
// *** waves/SIMD) all land 51-66us. Perf is INVARIANT to scheduling ->
// *** BANDWIDTH-bound: every variant streams 2 MB/CU at ~17 B/cy/CU
// *** (= 512 MB of L2/L3 re-reads at ~10 TB/s fabric). Only bytes/CU helps.
// *** R16: halve bytes/CU. Block = (branch, batch-group of 16, W-half):
// *** streams all 256 H x 128 W = 1 MB. W-half partial = min over its W of
// *** max over H = ONE scalar per nb -> partner blocks (bid^8, same XCD)
// *** exchange 16 scalars/depth via packed (value|epoch) uint64 atomics in
// *** the local L2. Math floor unchanged 13.7us; stream floor 1MB/17B/cy
// *** ~25us. Plain loads (fastest variant R0/R1); all asm machinery removed.
// ---------------------------------------------------------------------------
__global__ __launch_bounds__(512, 2) void prop_h_k(const _Float16* __restrict__ wsh,
                                                   const float* __restrict__ val,
                                                   float* __restrict__ out,
                                                   unsigned long long* __restrict__ xbuf) {
    const int bid  = blockIdx.x;
    const int x    = bid & 7;             // XCD id (dispatch round-robin)
    const int br   = x >> 2;              // branch -> XCD half
    const int wh   = (bid >> 3) & 1;      // W-half (partner = bid^8, same XCD)
    const int bg   = (bid >> 4) * 4 + (x & 3);   // batch group 0..63
    const int t    = threadIdx.x;
    const int wave = t >> 6;              // 0..7 = hq8 subset
    const int lane = t & 63;

    const int arrM = br ? 2 : 0;
    const int arrB = br ? 3 : 1;
    // uint2 units: HQ8BLK/4 = 16384 per (arr,hq8); row = 64 uint2.
    // Lane map: row = lane>>5 (2 rows/segment), w-slice = (lane&31)*4 halfs
    // of this block's W-half. Chunk = 4 rows (2 segments 128 uint2 apart);
    // 8 chunks/depth consume the 32-row slab; advance is uniform +256.
    const uint2* __restrict__ mp = (const uint2*)wsh + (size_t)(arrM * 8 + wave) * (HQ8BLK / 4)
                                   + (lane >> 5) * 64 + wh * 32 + (lane & 31);
    const uint2* __restrict__ bp = (const uint2*)wsh + (size_t)(arrB * 8 + wave) * (HQ8BLK / 4)
                                   + (lane >> 5) * 64 + wh * 32 + (lane & 31);

    __shared__ uint2 part[8][NB][32];   // 32 KB: [wave][nb][w-slice]
    __shared__ float qsp[NB];           // this block's W-half partial
    __shared__ float qs[NB];            // combined q

    h2 q2[NB];
#pragma unroll
    for (int nb = 0; nb < NB; ++nb) {
        const _Float16 qh = (_Float16)val[bg * NB + nb];   // block-uniform
        q2[nb].x = qh; q2[nb].y = qh;
    }

    union U2 { uint2 u; h2 h[2]; };
    union IH { int i; h2 h; };
    union { unsigned short us; _Float16 f; } ninf; ninf.us = 0xFC00;  // -inf
    h2 NEGINF; NEGINF.x = ninf.f; NEGINF.y = ninf.f;

    unsigned long long* xmine = xbuf + bid * NB;
    unsigned long long* xpart = xbuf + (bid ^ 8) * NB;

    for (int d = 0; d < NDEPTH; ++d) {
        h2 acc[NB][4];
#pragma unroll
        for (int nb = 0; nb < NB; ++nb)
#pragma unroll
            for (int k = 0; k < 4; ++k) acc[nb][k] = NEGINF;

#pragma unroll
        for (int c = 0; c < 8; ++c) {        // 8 chunks x 4 rows = 32 rows/depth
            U2 m0, m1, b0, b1;
            m0.u = mp[0]; m1.u = mp[128];
            b0.u = bp[0]; b1.u = bp[128];
            mp += 256; bp += 256;
#pragma unroll
            for (int nb = 0; nb < NB; ++nb) {
                const h2 qq = q2[nb];
                acc[nb][0] = __builtin_elementwise_max(
                    acc[nb][0], __builtin_elementwise_fma(qq, m0.h[0], b0.h[0]));
                acc[nb][1] = __builtin_elementwise_max(
                    acc[nb][1], __builtin_elementwise_fma(qq, m0.h[1], b0.h[1]));
                acc[nb][2] = __builtin_elementwise_max(
                    acc[nb][2], __builtin_elementwise_fma(qq, m1.h[0], b1.h[0]));
                acc[nb][3] = __builtin_elementwise_max(
                    acc[nb][3], __builtin_elementwise_fma(qq, m1.h[1], b1.h[1]));
            }
        }

        // H-row-class combine. acc[0..1]: rows == lane>>5 (mod 4)+{0};
        // acc[2..3]: +2. Merge k-pairs (same w), then xor32 (classes 0/1).
        if (true) {
#pragma unroll
            for (int nb = 0; nb < NB; ++nb) {
                h2 a0 = __builtin_elementwise_max(acc[nb][0], acc[nb][2]);
                h2 a1 = __builtin_elementwise_max(acc[nb][1], acc[nb][3]);
                IH ia, ob0, ob1;
                ia.h = a0; ob0.i = __shfl_xor(ia.i, 32);
                ia.h = a1; ob1.i = __shfl_xor(ia.i, 32);
                a0 = __builtin_elementwise_max(a0, ob0.h);
                a1 = __builtin_elementwise_max(a1, ob1.h);
                if (lane < 32) {
                    U2 st; st.h[0] = a0; st.h[1] = a1;
                    part[wave][nb][lane] = st.u;
                }
            }
        }
        __syncthreads();

        // reduce: thread t -> nb = t>>5 (16), j = t&31 (w-slice).
        // max over 8 waves (all 256 H), min over 4 halfs + 32 slices (128 W).
        {
            const int nb = t >> 5;
            const int j  = t & 31;
            U2 v; v.u = part[0][nb][j];
#pragma unroll
            for (int s2 = 1; s2 < 8; ++s2) {
                U2 w2; w2.u = part[s2][nb][j];
                v.h[0] = __builtin_elementwise_max(v.h[0], w2.h[0]);
                v.h[1] = __builtin_elementwise_max(v.h[1], w2.h[1]);
            }
            h2 mn = __builtin_elementwise_min(v.h[0], v.h[1]);
            float r = fminf((float)mn.x, (float)mn.y);
#pragma unroll
            for (int off = 16; off > 0; off >>= 1)
                r = fminf(r, __shfl_xor(r, off, 32));   // min within 32-lane group
            if (j == 0) qsp[nb] = r;
        }
        __syncthreads();

        // exchange W-half partials with partner block (same XCD -> local L2).
        // Packed (valuebits<<32 | epoch) self-validating atomics; reader
        // clears with exch(0) -> mailbox returns to 0 for next launch.
        if (t < NB) {
            union { float f; unsigned u; } pv; pv.f = qsp[t];
            atomicExch(&xmine[t],
                       ((unsigned long long)pv.u << 32) | (unsigned)(d + 1));
            unsigned long long got;
            for (;;) {
                got = atomicExch(&xpart[t], 0ULL);
                if ((unsigned)(got & 0xFFFFFFFFULL) == (unsigned)(d + 1)) break;
                __builtin_amdgcn_s_sleep(1);
            }
            union { unsigned u; float f; } qv; qv.u = (unsigned)(got >> 32);
            qs[t] = fminf(qsp[t], qv.f);
        }
        __syncthreads();
#pragma unroll
        for (int nb = 0; nb < NB; ++nb) {
            const _Float16 qh = (_Float16)qs[nb];
            q2[nb].x = qh; q2[nb].y = qh;
        }
        // part[] rewritten only after next depth's math -> safe w.r.t. readers
    }

    if (wh == 0 && t < NB) out[br * NBATCH + bg * NB + t] = qs[t];
}

// ---------------------------------------------------------------------------
extern "C" void kernel_launch(void* const* d_in, const int* in_sizes, int n_in,
                              void* d_out, int out_size, void* d_ws, size_t ws_size,
                              hipStream_t stream) {
    const float* val = (const float*)d_in[0];
    const float* M1  = (const float*)d_in[1];
    const float* B1  = (const float*)d_in[2];
    const float* M2  = (const float*)d_in[3];
    const float* B2  = (const float*)d_in[4];
    float*    out = (float*)d_out;
    _Float16* wsh = (_Float16*)d_ws;   // 4 MiB data (ws >= 8 MiB, R2)
    unsigned long long* xbuf =
        (unsigned long long*)((char*)d_ws + XBUF_OFF);   // 32 KB mailbox

    transpose_half_k<<<dim3(512), dim3(256), 0, stream>>>(M1, B1, M2, B2, wsh, xbuf);
    prop_h_k<<<dim3(256), dim3(512), 0, stream>>>(wsh, val, out, xbuf);
}